// Round 5
// baseline (370.589 us; speedup 1.0000x reference)
//
#include <hip/hip_runtime.h>
#include <cmath>

// Problem constants
#define NBATCH 16
#define NCH    128      // C = channels = HIDDEN
#define NPIX   16384    // H*W
#define NSLOT  32       // one partial slot per pixel-group (no atomics)

// Workspace layout (floats):
//   Spart [16][NSLOT][128] ; Apart [16][NSLOT][4][32][32]
//   then bf16 Mbf [16][128][128]
#define WS_S_OFF   0
#define WS_A_OFF   (NBATCH * NSLOT * 128)
#define WS_TOT_FLOATS (WS_A_OFF + NBATCH * NSLOT * 4096)
#define WS_MBF_BYTE ((size_t)WS_TOT_FLOATS * 4)

typedef __bf16 bf16x8 __attribute__((ext_vector_type(8)));
typedef __bf16 bf16x4 __attribute__((ext_vector_type(4)));
typedef __bf16 bf16x2 __attribute__((ext_vector_type(2)));
typedef float  f32x4  __attribute__((ext_vector_type(4)));

#define MFMA16(a, b, c) __builtin_amdgcn_mfma_f32_16x16x32_bf16((a), (b), (c), 0, 0, 0)

// Barrier without the compiler's vmcnt(0) drain: LDS-only fence + s_barrier.
// Keeps prefetch global_loads (to VGPRs) in flight across the barrier.
__device__ __forceinline__ void barrier_lds() {
    asm volatile("s_waitcnt lgkmcnt(0)\n\ts_barrier" ::: "memory");
}

// ---------------------------------------------------------------------------
// K1: 512 blocks = (32 n-groups) x (16 batches), 8 chunks of 64 pixels each.
// Double-buffered Xs -> ONE barrier per chunk: a wave reaching barrier i+1
// has finished its reads of buffer (i&1) by program order, so restaging the
// alternate buffer needs no second barrier. Inner compute verbatim from the
// verified round-1/4 kernel.
// ---------------------------------------------------------------------------
__global__ __launch_bounds__(256, 2) void k1_partials(const float* __restrict__ x,
                                                      const float* __restrict__ w_qkv,
                                                      float* __restrict__ ws)
{
    const int b = blockIdx.y;
    const int g = blockIdx.x;           // 0..31
    const int t = threadIdx.x;
    const int w = t >> 6;               // wave == head
    const int l = t & 63;
    const int lm = l & 15;              // MFMA m/n/col lane index
    const int q  = l >> 4;              // quad

    __shared__ __align__(16) __bf16 Xs[2][64][136];   // [buf][pix][ch] (34 KB)
    __shared__ __align__(16) __bf16 Ee[4][32][20][2]; // pair-packed E (10 KB)
    __shared__ __align__(16) __bf16 Vv[4][32][20][2]; // pair-packed V (10 KB)

    const float* wkv = w_qkv + 128 * NCH;
    bf16x8 wfrag[4][4];   // rt 0,1 = k-rows of head w, rt 2,3 = v-rows
#pragma unroll
    for (int rt = 0; rt < 4; ++rt) {
        const int row = (rt < 2) ? (w * 32 + rt * 16 + lm)
                                 : (128 + w * 32 + (rt - 2) * 16 + lm);
#pragma unroll
        for (int ks = 0; ks < 4; ++ks) {
            const float* src = wkv + row * NCH + ks * 32 + q * 8;
            float4 p0 = *(const float4*)src;
            float4 p1 = *(const float4*)(src + 4);
            bf16x8 f;
            f[0] = (__bf16)p0.x; f[1] = (__bf16)p0.y; f[2] = (__bf16)p0.z; f[3] = (__bf16)p0.w;
            f[4] = (__bf16)p1.x; f[5] = (__bf16)p1.y; f[6] = (__bf16)p1.z; f[7] = (__bf16)p1.w;
            wfrag[rt][ks] = f;
        }
    }

    f32x4 a_acc[2][2];
#pragma unroll
    for (int dt = 0; dt < 2; ++dt)
#pragma unroll
        for (int et = 0; et < 2; ++et) a_acc[dt][et] = (f32x4)0.f;
    float s8[8];
#pragma unroll
    for (int j = 0; j < 8; ++j) s8[j] = 0.f;

    float fx[8][4];
    const float* xbase = x + (size_t)(b * NCH + w * 32) * NPIX + l;

    {   // issue loads for chunk 0
        const int n0 = g * 64;
#pragma unroll
        for (int rq = 0; rq < 8; ++rq) {
            const float* xb = xbase + (size_t)(rq * 4) * NPIX + n0;
            fx[rq][0] = xb[0];
            fx[rq][1] = xb[NPIX];
            fx[rq][2] = xb[2 * NPIX];
            fx[rq][3] = xb[3 * NPIX];
        }
    }

    for (int ci = 0; ci < 8; ++ci) {
        const int cur = ci & 1;
#pragma unroll
        for (int rq = 0; rq < 8; ++rq) {
            bf16x4 pk;
            pk[0] = (__bf16)fx[rq][0]; pk[1] = (__bf16)fx[rq][1];
            pk[2] = (__bf16)fx[rq][2]; pk[3] = (__bf16)fx[rq][3];
            *(bf16x4*)&Xs[cur][l][w * 32 + rq * 4] = pk;
        }
        if (ci < 7) {
            const int n0 = (g + (ci + 1) * 32) * 64;
#pragma unroll
            for (int rq = 0; rq < 8; ++rq) {
                const float* xb = xbase + (size_t)(rq * 4) * NPIX + n0;
                fx[rq][0] = xb[0];
                fx[rq][1] = xb[NPIX];
                fx[rq][2] = xb[2 * NPIX];
                fx[rq][3] = xb[3 * NPIX];
            }
        }
        barrier_lds();   // Xs[cur] ready (single barrier per chunk)

        f32x4 acc[4][4];
#pragma unroll
        for (int rt = 0; rt < 4; ++rt)
#pragma unroll
            for (int ct = 0; ct < 4; ++ct) acc[rt][ct] = (f32x4)0.f;

#pragma unroll
        for (int ks = 0; ks < 4; ++ks) {
            bf16x8 bf[4];
#pragma unroll
            for (int ct = 0; ct < 4; ++ct)
                bf[ct] = *(const bf16x8*)&Xs[cur][ct * 16 + lm][ks * 32 + q * 8];
#pragma unroll
            for (int rt = 0; rt < 4; ++rt)
#pragma unroll
                for (int ct = 0; ct < 4; ++ct)
                    acc[rt][ct] = MFMA16(wfrag[rt][ks], bf[ct], acc[rt][ct]);
        }

#pragma unroll
        for (int hf = 0; hf < 2; ++hf) {
#pragma unroll
            for (int rt = 0; rt < 2; ++rt) {
                f32x4 v0 = acc[rt][hf * 2 + 0];
                f32x4 v1 = acc[rt][hf * 2 + 1];
#pragma unroll
                for (int r = 0; r < 4; ++r) {
                    float e0 = __expf(v0[r]);
                    float e1 = __expf(v1[r]);
                    s8[rt * 4 + r] += e0 + e1;
                    bf16x2 pw; pw[0] = (__bf16)e0; pw[1] = (__bf16)e1;
                    *(bf16x2*)&Ee[w][rt * 16 + q * 4 + r][lm][0] = pw;
                }
            }
#pragma unroll
            for (int rt = 0; rt < 2; ++rt) {
                f32x4 v0 = acc[rt + 2][hf * 2 + 0];
                f32x4 v1 = acc[rt + 2][hf * 2 + 1];
#pragma unroll
                for (int r = 0; r < 4; ++r) {
                    bf16x2 pw; pw[0] = (__bf16)v0[r]; pw[1] = (__bf16)v1[r];
                    *(bf16x2*)&Vv[w][rt * 16 + q * 4 + r][lm][0] = pw;
                }
            }
            {
                bf16x8 ea[2], vb[2];
#pragma unroll
                for (int dt = 0; dt < 2; ++dt)
                    ea[dt] = *(const bf16x8*)&Ee[w][dt * 16 + lm][q * 4][0];
#pragma unroll
                for (int et = 0; et < 2; ++et)
                    vb[et] = *(const bf16x8*)&Vv[w][et * 16 + lm][q * 4][0];
#pragma unroll
                for (int dt = 0; dt < 2; ++dt)
#pragma unroll
                    for (int et = 0; et < 2; ++et)
                        a_acc[dt][et] = MFMA16(ea[dt], vb[et], a_acc[dt][et]);
            }
        }
        // no trailing barrier: next chunk writes the alternate Xs buffer
    }

    // epilogue: plain stores to this block's private slot
#pragma unroll
    for (int j = 0; j < 8; ++j) {
        float v = s8[j];
        v += __shfl_xor(v, 1);
        v += __shfl_xor(v, 2);
        v += __shfl_xor(v, 4);
        v += __shfl_xor(v, 8);
        s8[j] = v;
    }
    if (lm == 0) {
        float* Sp = ws + WS_S_OFF + (size_t)(b * NSLOT + g) * 128;
#pragma unroll
        for (int rt2 = 0; rt2 < 2; ++rt2)
#pragma unroll
            for (int r = 0; r < 4; ++r)
                Sp[w * 32 + rt2 * 16 + q * 4 + r] = s8[rt2 * 4 + r];
    }
    {
        float* Ab = ws + WS_A_OFF + (size_t)((b * NSLOT + g) * 4 + w) * 1024;
#pragma unroll
        for (int dt = 0; dt < 2; ++dt)
#pragma unroll
            for (int et = 0; et < 2; ++et)
#pragma unroll
                for (int r = 0; r < 4; ++r)
                    Ab[(dt * 16 + q * 4 + r) * 32 + et * 16 + lm] = a_acc[dt][et][r];
    }
}

// ---------------------------------------------------------------------------
// K2: one block per batch (grid 16). ctx = (sum_slot A)/(sum_slot S) with
// f32x4 vectorized slot reduce; T = w_out @ ctx (fp32, bf16 rows in LDS);
// M' = scale * T @ Wq via MFMA -> Mbf. (verbatim from verified round-4)
// ---------------------------------------------------------------------------
__global__ __launch_bounds__(256) void k2_mprime(const float* __restrict__ w_qkv,
                                                 const float* __restrict__ w_out,
                                                 const float* __restrict__ ws,
                                                 __bf16* __restrict__ Mbf)
{
    const int b = blockIdx.x;
    const int t = threadIdx.x;
    const int w = t >> 6, l = t & 63;
    const int lm = l & 15, q = l >> 4;

    __shared__ __align__(16) float  ctx[4096];   // [h][d][e] fp32, 16 KB
    __shared__ float  Sinv[128];
    __shared__ __align__(16) __bf16 T[128][136]; // bf16 T rows, 34 KB

    if (t < 128) {
        float s = 0.f;
#pragma unroll
        for (int sl = 0; sl < NSLOT; ++sl)
            s += ws[WS_S_OFF + (size_t)(b * NSLOT + sl) * 128 + t];
        Sinv[t] = 1.f / s;
    }
    __syncthreads();

    for (int c4 = t; c4 < 1024; c4 += 256) {
        f32x4 a = (f32x4)0.f;
#pragma unroll
        for (int sl = 0; sl < NSLOT; ++sl)
            a += *(const f32x4*)&ws[WS_A_OFF + (size_t)(b * NSLOT + sl) * 4096 + c4 * 4];
        const float si = Sinv[c4 >> 3];
        *(f32x4*)&ctx[c4 * 4] = a * si;
    }
    __syncthreads();

    {
        const int o    = t >> 1;
        const int half = t & 1;        // hd range: half*64 .. half*64+63
        float wo[64];
#pragma unroll
        for (int e4 = 0; e4 < 64; e4 += 4)
            *(float4*)&wo[e4] = *(const float4*)&w_out[o * NCH + half * 64 + e4];
#pragma unroll
        for (int j8 = 0; j8 < 8; ++j8) {
            bf16x8 pk;
#pragma unroll
            for (int jj = 0; jj < 8; ++jj) {
                const int j    = j8 * 8 + jj;   // 0..63
                const int hl   = j >> 5;        // 0/1 within half
                const int drow = j & 31;
                const float* crow = &ctx[(half * 2 + hl) * 1024 + drow * 32];
                float s = 0.f;
#pragma unroll
                for (int e4 = 0; e4 < 8; ++e4) {
                    f32x4 cv = *(const f32x4*)&crow[e4 * 4];
                    s = fmaf(wo[hl * 32 + e4 * 4 + 0], cv[0], s);
                    s = fmaf(wo[hl * 32 + e4 * 4 + 1], cv[1], s);
                    s = fmaf(wo[hl * 32 + e4 * 4 + 2], cv[2], s);
                    s = fmaf(wo[hl * 32 + e4 * 4 + 3], cv[3], s);
                }
                pk[jj] = (__bf16)s;
            }
            *(bf16x8*)&T[o][half * 64 + j8 * 8] = pk;
        }
    }
    __syncthreads();

    {
        f32x4 acc[2][8];
#pragma unroll
        for (int rt = 0; rt < 2; ++rt)
#pragma unroll
            for (int ct = 0; ct < 8; ++ct) acc[rt][ct] = (f32x4)0.f;

#pragma unroll
        for (int ks = 0; ks < 4; ++ks) {
            bf16x8 afr[2];
#pragma unroll
            for (int rt = 0; rt < 2; ++rt)
                afr[rt] = *(const bf16x8*)&T[w * 32 + rt * 16 + lm][ks * 32 + q * 8];
#pragma unroll
            for (int ct = 0; ct < 8; ++ct) {
                bf16x8 bfr;
#pragma unroll
                for (int j = 0; j < 8; ++j)
                    bfr[j] = (__bf16)w_qkv[(size_t)(ks * 32 + q * 8 + j) * NCH + ct * 16 + lm];
#pragma unroll
                for (int rt = 0; rt < 2; ++rt)
                    acc[rt][ct] = MFMA16(afr[rt], bfr, acc[rt][ct]);
            }
        }

        const float scale = 0.17677669529663687f;  // 32^-0.5
        __bf16* Mb = Mbf + (size_t)b * NCH * NCH;
#pragma unroll
        for (int rt = 0; rt < 2; ++rt)
#pragma unroll
            for (int r = 0; r < 4; ++r) {
                const int o = w * 32 + rt * 16 + q * 4 + r;
#pragma unroll
                for (int ct = 0; ct < 8; ++ct)
                    Mb[(size_t)o * NCH + ct * 16 + lm] = (__bf16)(acc[rt][ct][r] * scale);
            }
    }
}

// ---------------------------------------------------------------------------
// K3: y[b] = M'[b] @ X[b] + bias via MFMA. Four 64-px tiles per block
// (grid 64 x 16 = 1024 blocks = 4/CU), double-buffered Xs -> one barrier per
// tile, rolling register prefetch. Inner tile loop verbatim from round-1/4.
// ---------------------------------------------------------------------------
__global__ __launch_bounds__(256, 4) void k3_out(const float* __restrict__ x,
                                                 const float* __restrict__ bias,
                                                 const __bf16* __restrict__ Mbf,
                                                 float* __restrict__ y)
{
    const int b  = blockIdx.y;
    const int t  = threadIdx.x;
    const int w  = t >> 6, l = t & 63;
    const int lm = l & 15, q = l >> 4;

    __shared__ __align__(16) __bf16 Xs[2][64][136];   // 34.8 KB (<=40 KB for 4/CU)

    const __bf16* Mb = Mbf + (size_t)b * NCH * NCH;
    bf16x8 mfrag[2][4];
#pragma unroll
    for (int rt = 0; rt < 2; ++rt)
#pragma unroll
        for (int ks = 0; ks < 4; ++ks)
            mfrag[rt][ks] = *(const bf16x8*)&Mb[(size_t)(w * 32 + rt * 16 + lm) * NCH + ks * 32 + q * 8];

    float bbr[2][4];
#pragma unroll
    for (int rt = 0; rt < 2; ++rt)
#pragma unroll
        for (int r = 0; r < 4; ++r)
            bbr[rt][r] = bias[w * 32 + rt * 16 + q * 4 + r];

    const int base = blockIdx.x * 256;
    const float* xb3 = x + (size_t)(b * NCH + w * 32) * NPIX + l;
    float fx[8][4];
    {   // prefetch tile 0
#pragma unroll
        for (int rq = 0; rq < 8; ++rq) {
            const float* xb = xb3 + (size_t)(rq * 4) * NPIX + base;
            fx[rq][0] = xb[0];
            fx[rq][1] = xb[NPIX];
            fx[rq][2] = xb[2 * NPIX];
            fx[rq][3] = xb[3 * NPIX];
        }
    }

    for (int jj = 0; jj < 4; ++jj) {
        const int cur = jj & 1;
        // stage prefetched tile into the alternate buffer
#pragma unroll
        for (int rq = 0; rq < 8; ++rq) {
            bf16x4 pk;
            pk[0] = (__bf16)fx[rq][0]; pk[1] = (__bf16)fx[rq][1];
            pk[2] = (__bf16)fx[rq][2]; pk[3] = (__bf16)fx[rq][3];
            *(bf16x4*)&Xs[cur][l][w * 32 + rq * 4] = pk;
        }
        if (jj < 3) {   // prefetch next tile (stays in flight across barrier)
            const int n1 = base + (jj + 1) * 64;
#pragma unroll
            for (int rq = 0; rq < 8; ++rq) {
                const float* xb = xb3 + (size_t)(rq * 4) * NPIX + n1;
                fx[rq][0] = xb[0];
                fx[rq][1] = xb[NPIX];
                fx[rq][2] = xb[2 * NPIX];
                fx[rq][3] = xb[3 * NPIX];
            }
        }
        barrier_lds();   // Xs[cur] ready (single barrier per tile)

        f32x4 acc[2][4];
#pragma unroll
        for (int rt = 0; rt < 2; ++rt)
#pragma unroll
            for (int ct = 0; ct < 4; ++ct) acc[rt][ct] = (f32x4)0.f;

#pragma unroll
        for (int ks = 0; ks < 4; ++ks) {
            bf16x8 bf[4];
#pragma unroll
            for (int ct = 0; ct < 4; ++ct)
                bf[ct] = *(const bf16x8*)&Xs[cur][ct * 16 + lm][ks * 32 + q * 8];
#pragma unroll
            for (int rt = 0; rt < 2; ++rt)
#pragma unroll
                for (int ct = 0; ct < 4; ++ct)
                    acc[rt][ct] = MFMA16(mfrag[rt][ks], bf[ct], acc[rt][ct]);
        }

        const int n0 = base + jj * 64;
#pragma unroll
        for (int rt = 0; rt < 2; ++rt) {
#pragma unroll
            for (int r = 0; r < 4; ++r) {
                const int row = w * 32 + rt * 16 + q * 4 + r;
                float* yp = y + (size_t)(b * NCH + row) * NPIX + n0 + lm;
#pragma unroll
                for (int ct = 0; ct < 4; ++ct)
                    yp[ct * 16] = acc[rt][ct][r] + bbr[rt][r];
            }
        }
        // no trailing barrier: next tile writes the alternate Xs buffer
    }
}

extern "C" void kernel_launch(void* const* d_in, const int* in_sizes, int n_in,
                              void* d_out, int out_size, void* d_ws, size_t ws_size,
                              hipStream_t stream) {
    (void)in_sizes; (void)n_in; (void)out_size; (void)ws_size;
    const float* x     = (const float*)d_in[0];
    const float* w_qkv = (const float*)d_in[1];
    const float* w_out = (const float*)d_in[2];
    const float* b_out = (const float*)d_in[3];
    float*  y   = (float*)d_out;
    float*  ws  = (float*)d_ws;
    __bf16* Mbf = (__bf16*)((char*)d_ws + WS_MBF_BYTE);

    // No memset needed: every Spart/Apart element is fully written by k1
    // before k2 reads it (slot-per-group, no atomics); k1->k2 and k2->k3
    // visibility is guaranteed by kernel dispatch boundaries.
    k1_partials<<<dim3(NSLOT, NBATCH),      256, 0, stream>>>(x, w_qkv, ws);
    k2_mprime  <<<dim3(NBATCH),             256, 0, stream>>>(w_qkv, w_out, ws, Mbf);
    k3_out     <<<dim3(NPIX / 256, NBATCH), 256, 0, stream>>>(x, b_out, Mbf, y);
}

// Round 6
// 290.086 us; speedup vs baseline: 1.2775x; 1.2775x over previous
//
#include <hip/hip_runtime.h>
#include <cmath>

// Problem constants
#define NBATCH 16
#define NCH    128      // C = channels = HIDDEN
#define NPIX   16384    // H*W
#define NSLOT  32       // one partial slot per pixel-group (no atomics)

// Workspace layout (floats):
//   Spart [16][NSLOT][128] ; Apart [16][NSLOT][4][32][32]
//   then bf16 Mbf [16][128][128]
#define WS_S_OFF   0
#define WS_A_OFF   (NBATCH * NSLOT * 128)
#define WS_TOT_FLOATS (WS_A_OFF + NBATCH * NSLOT * 4096)
#define WS_MBF_BYTE ((size_t)WS_TOT_FLOATS * 4)

typedef __bf16 bf16x8 __attribute__((ext_vector_type(8)));
typedef __bf16 bf16x4 __attribute__((ext_vector_type(4)));
typedef __bf16 bf16x2 __attribute__((ext_vector_type(2)));
typedef float  f32x4  __attribute__((ext_vector_type(4)));

#define MFMA16(a, b, c) __builtin_amdgcn_mfma_f32_16x16x32_bf16((a), (b), (c), 0, 0, 0)

// Barrier without the compiler's vmcnt(0) drain: LDS-only fence + s_barrier.
// Keeps prefetch global_loads (to VGPRs) in flight across the barrier.
__device__ __forceinline__ void barrier_lds() {
    asm volatile("s_waitcnt lgkmcnt(0)\n\ts_barrier" ::: "memory");
}

// ---------------------------------------------------------------------------
// K1: 512 blocks = (32 n-groups) x (16 batches), 8 chunks of 64 pixels each.
// (verbatim from the verified round-4 kernel — r5's dbuf variant reverted)
// ---------------------------------------------------------------------------
__global__ __launch_bounds__(256, 2) void k1_partials(const float* __restrict__ x,
                                                      const float* __restrict__ w_qkv,
                                                      float* __restrict__ ws)
{
    const int b = blockIdx.y;
    const int g = blockIdx.x;           // 0..31
    const int t = threadIdx.x;
    const int w = t >> 6;               // wave == head
    const int l = t & 63;
    const int lm = l & 15;              // MFMA m/n/col lane index
    const int q  = l >> 4;              // quad

    __shared__ __align__(16) __bf16 Xs[64][136];      // [pix][ch] (17.0 KB)
    __shared__ __align__(16) __bf16 Ee[4][32][20][2]; // pair-packed E (10 KB)
    __shared__ __align__(16) __bf16 Vv[4][32][20][2]; // pair-packed V (10 KB)

    const float* wkv = w_qkv + 128 * NCH;
    bf16x8 wfrag[4][4];   // rt 0,1 = k-rows of head w, rt 2,3 = v-rows
#pragma unroll
    for (int rt = 0; rt < 4; ++rt) {
        const int row = (rt < 2) ? (w * 32 + rt * 16 + lm)
                                 : (128 + w * 32 + (rt - 2) * 16 + lm);
#pragma unroll
        for (int ks = 0; ks < 4; ++ks) {
            const float* src = wkv + row * NCH + ks * 32 + q * 8;
            float4 p0 = *(const float4*)src;
            float4 p1 = *(const float4*)(src + 4);
            bf16x8 f;
            f[0] = (__bf16)p0.x; f[1] = (__bf16)p0.y; f[2] = (__bf16)p0.z; f[3] = (__bf16)p0.w;
            f[4] = (__bf16)p1.x; f[5] = (__bf16)p1.y; f[6] = (__bf16)p1.z; f[7] = (__bf16)p1.w;
            wfrag[rt][ks] = f;
        }
    }

    f32x4 a_acc[2][2];
#pragma unroll
    for (int dt = 0; dt < 2; ++dt)
#pragma unroll
        for (int et = 0; et < 2; ++et) a_acc[dt][et] = (f32x4)0.f;
    float s8[8];
#pragma unroll
    for (int j = 0; j < 8; ++j) s8[j] = 0.f;

    float fx[8][4];
    const float* xbase = x + (size_t)(b * NCH + w * 32) * NPIX + l;

    {   // issue loads for chunk 0
        const int n0 = g * 64;
#pragma unroll
        for (int rq = 0; rq < 8; ++rq) {
            const float* xb = xbase + (size_t)(rq * 4) * NPIX + n0;
            fx[rq][0] = xb[0];
            fx[rq][1] = xb[NPIX];
            fx[rq][2] = xb[2 * NPIX];
            fx[rq][3] = xb[3 * NPIX];
        }
    }

    for (int ci = 0; ci < 8; ++ci) {
#pragma unroll
        for (int rq = 0; rq < 8; ++rq) {
            bf16x4 pk;
            pk[0] = (__bf16)fx[rq][0]; pk[1] = (__bf16)fx[rq][1];
            pk[2] = (__bf16)fx[rq][2]; pk[3] = (__bf16)fx[rq][3];
            *(bf16x4*)&Xs[l][w * 32 + rq * 4] = pk;
        }
        if (ci < 7) {
            const int n0 = (g + (ci + 1) * 32) * 64;
#pragma unroll
            for (int rq = 0; rq < 8; ++rq) {
                const float* xb = xbase + (size_t)(rq * 4) * NPIX + n0;
                fx[rq][0] = xb[0];
                fx[rq][1] = xb[NPIX];
                fx[rq][2] = xb[2 * NPIX];
                fx[rq][3] = xb[3 * NPIX];
            }
        }
        barrier_lds();   // Xs ready

        f32x4 acc[4][4];
#pragma unroll
        for (int rt = 0; rt < 4; ++rt)
#pragma unroll
            for (int ct = 0; ct < 4; ++ct) acc[rt][ct] = (f32x4)0.f;

#pragma unroll
        for (int ks = 0; ks < 4; ++ks) {
            bf16x8 bf[4];
#pragma unroll
            for (int ct = 0; ct < 4; ++ct)
                bf[ct] = *(const bf16x8*)&Xs[ct * 16 + lm][ks * 32 + q * 8];
#pragma unroll
            for (int rt = 0; rt < 4; ++rt)
#pragma unroll
                for (int ct = 0; ct < 4; ++ct)
                    acc[rt][ct] = MFMA16(wfrag[rt][ks], bf[ct], acc[rt][ct]);
        }

#pragma unroll
        for (int hf = 0; hf < 2; ++hf) {
#pragma unroll
            for (int rt = 0; rt < 2; ++rt) {
                f32x4 v0 = acc[rt][hf * 2 + 0];
                f32x4 v1 = acc[rt][hf * 2 + 1];
#pragma unroll
                for (int r = 0; r < 4; ++r) {
                    float e0 = __expf(v0[r]);
                    float e1 = __expf(v1[r]);
                    s8[rt * 4 + r] += e0 + e1;
                    bf16x2 pw; pw[0] = (__bf16)e0; pw[1] = (__bf16)e1;
                    *(bf16x2*)&Ee[w][rt * 16 + q * 4 + r][lm][0] = pw;
                }
            }
#pragma unroll
            for (int rt = 0; rt < 2; ++rt) {
                f32x4 v0 = acc[rt + 2][hf * 2 + 0];
                f32x4 v1 = acc[rt + 2][hf * 2 + 1];
#pragma unroll
                for (int r = 0; r < 4; ++r) {
                    bf16x2 pw; pw[0] = (__bf16)v0[r]; pw[1] = (__bf16)v1[r];
                    *(bf16x2*)&Vv[w][rt * 16 + q * 4 + r][lm][0] = pw;
                }
            }
            {
                bf16x8 ea[2], vb[2];
#pragma unroll
                for (int dt = 0; dt < 2; ++dt)
                    ea[dt] = *(const bf16x8*)&Ee[w][dt * 16 + lm][q * 4][0];
#pragma unroll
                for (int et = 0; et < 2; ++et)
                    vb[et] = *(const bf16x8*)&Vv[w][et * 16 + lm][q * 4][0];
#pragma unroll
                for (int dt = 0; dt < 2; ++dt)
#pragma unroll
                    for (int et = 0; et < 2; ++et)
                        a_acc[dt][et] = MFMA16(ea[dt], vb[et], a_acc[dt][et]);
            }
        }
        barrier_lds();   // Xs consumed; safe to restage
    }

    // epilogue: plain stores to this block's private slot
#pragma unroll
    for (int j = 0; j < 8; ++j) {
        float v = s8[j];
        v += __shfl_xor(v, 1);
        v += __shfl_xor(v, 2);
        v += __shfl_xor(v, 4);
        v += __shfl_xor(v, 8);
        s8[j] = v;
    }
    if (lm == 0) {
        float* Sp = ws + WS_S_OFF + (size_t)(b * NSLOT + g) * 128;
#pragma unroll
        for (int rt2 = 0; rt2 < 2; ++rt2)
#pragma unroll
            for (int r = 0; r < 4; ++r)
                Sp[w * 32 + rt2 * 16 + q * 4 + r] = s8[rt2 * 4 + r];
    }
    {
        float* Ab = ws + WS_A_OFF + (size_t)((b * NSLOT + g) * 4 + w) * 1024;
#pragma unroll
        for (int dt = 0; dt < 2; ++dt)
#pragma unroll
            for (int et = 0; et < 2; ++et)
#pragma unroll
                for (int r = 0; r < 4; ++r)
                    Ab[(dt * 16 + q * 4 + r) * 32 + et * 16 + lm] = a_acc[dt][et][r];
    }
}

// ---------------------------------------------------------------------------
// K2: one block per batch (grid 16). ctx = (sum_slot A)/(sum_slot S) with
// f32x4 vectorized slot reduce; T = w_out @ ctx (fp32, bf16 rows in LDS);
// M' = scale * T @ Wq via MFMA -> Mbf. (verbatim from verified round-4)
// ---------------------------------------------------------------------------
__global__ __launch_bounds__(256) void k2_mprime(const float* __restrict__ w_qkv,
                                                 const float* __restrict__ w_out,
                                                 const float* __restrict__ ws,
                                                 __bf16* __restrict__ Mbf)
{
    const int b = blockIdx.x;
    const int t = threadIdx.x;
    const int w = t >> 6, l = t & 63;
    const int lm = l & 15, q = l >> 4;

    __shared__ __align__(16) float  ctx[4096];   // [h][d][e] fp32, 16 KB
    __shared__ float  Sinv[128];
    __shared__ __align__(16) __bf16 T[128][136]; // bf16 T rows, 34 KB

    if (t < 128) {
        float s = 0.f;
#pragma unroll
        for (int sl = 0; sl < NSLOT; ++sl)
            s += ws[WS_S_OFF + (size_t)(b * NSLOT + sl) * 128 + t];
        Sinv[t] = 1.f / s;
    }
    __syncthreads();

    for (int c4 = t; c4 < 1024; c4 += 256) {
        f32x4 a = (f32x4)0.f;
#pragma unroll
        for (int sl = 0; sl < NSLOT; ++sl)
            a += *(const f32x4*)&ws[WS_A_OFF + (size_t)(b * NSLOT + sl) * 4096 + c4 * 4];
        const float si = Sinv[c4 >> 3];
        *(f32x4*)&ctx[c4 * 4] = a * si;
    }
    __syncthreads();

    {
        const int o    = t >> 1;
        const int half = t & 1;        // hd range: half*64 .. half*64+63
        float wo[64];
#pragma unroll
        for (int e4 = 0; e4 < 64; e4 += 4)
            *(float4*)&wo[e4] = *(const float4*)&w_out[o * NCH + half * 64 + e4];
#pragma unroll
        for (int j8 = 0; j8 < 8; ++j8) {
            bf16x8 pk;
#pragma unroll
            for (int jj = 0; jj < 8; ++jj) {
                const int j    = j8 * 8 + jj;   // 0..63
                const int hl   = j >> 5;        // 0/1 within half
                const int drow = j & 31;
                const float* crow = &ctx[(half * 2 + hl) * 1024 + drow * 32];
                float s = 0.f;
#pragma unroll
                for (int e4 = 0; e4 < 8; ++e4) {
                    f32x4 cv = *(const f32x4*)&crow[e4 * 4];
                    s = fmaf(wo[hl * 32 + e4 * 4 + 0], cv[0], s);
                    s = fmaf(wo[hl * 32 + e4 * 4 + 1], cv[1], s);
                    s = fmaf(wo[hl * 32 + e4 * 4 + 2], cv[2], s);
                    s = fmaf(wo[hl * 32 + e4 * 4 + 3], cv[3], s);
                }
                pk[jj] = (__bf16)s;
            }
            *(bf16x8*)&T[o][half * 64 + j8 * 8] = pk;
        }
    }
    __syncthreads();

    {
        f32x4 acc[2][8];
#pragma unroll
        for (int rt = 0; rt < 2; ++rt)
#pragma unroll
            for (int ct = 0; ct < 8; ++ct) acc[rt][ct] = (f32x4)0.f;

#pragma unroll
        for (int ks = 0; ks < 4; ++ks) {
            bf16x8 afr[2];
#pragma unroll
            for (int rt = 0; rt < 2; ++rt)
                afr[rt] = *(const bf16x8*)&T[w * 32 + rt * 16 + lm][ks * 32 + q * 8];
#pragma unroll
            for (int ct = 0; ct < 8; ++ct) {
                bf16x8 bfr;
#pragma unroll
                for (int j = 0; j < 8; ++j)
                    bfr[j] = (__bf16)w_qkv[(size_t)(ks * 32 + q * 8 + j) * NCH + ct * 16 + lm];
#pragma unroll
                for (int rt = 0; rt < 2; ++rt)
                    acc[rt][ct] = MFMA16(afr[rt], bfr, acc[rt][ct]);
            }
        }

        const float scale = 0.17677669529663687f;  // 32^-0.5
        __bf16* Mb = Mbf + (size_t)b * NCH * NCH;
#pragma unroll
        for (int rt = 0; rt < 2; ++rt)
#pragma unroll
            for (int r = 0; r < 4; ++r) {
                const int o = w * 32 + rt * 16 + q * 4 + r;
#pragma unroll
                for (int ct = 0; ct < 8; ++ct)
                    Mb[(size_t)o * NCH + ct * 16 + lm] = (__bf16)(acc[rt][ct][r] * scale);
            }
    }
}

// ---------------------------------------------------------------------------
// K3: y[b] = M'[b] @ X[b] + bias via MFMA. Round-4 structure (two 64-px
// tiles per block, grid 2048, register prefetch) with ONE change: the y
// epilogue stages each wave's 16x64 fp32 sub-tile in per-wave LDS (row
// stride 68 floats) and stores global_store_dwordx4 — every store
// instruction writes 4 x 256 B contiguous row segments instead of 4 B
// scattered dwords (r5 counters: WRITE_SIZE 234 MB vs 134 MB ideal).
// ---------------------------------------------------------------------------
__global__ __launch_bounds__(256, 4) void k3_out(const float* __restrict__ x,
                                                 const float* __restrict__ bias,
                                                 const __bf16* __restrict__ Mbf,
                                                 float* __restrict__ y)
{
    const int b  = blockIdx.y;
    const int t  = threadIdx.x;
    const int w  = t >> 6, l = t & 63;
    const int lm = l & 15, q = l >> 4;

    __shared__ __align__(16) __bf16 Xs[64][136];   // 17.0 KB
    __shared__ __align__(16) float  Ys[4][16][68]; // per-wave y staging, 17.0 KB

    const __bf16* Mb = Mbf + (size_t)b * NCH * NCH;
    bf16x8 mfrag[2][4];
#pragma unroll
    for (int rt = 0; rt < 2; ++rt)
#pragma unroll
        for (int ks = 0; ks < 4; ++ks)
            mfrag[rt][ks] = *(const bf16x8*)&Mb[(size_t)(w * 32 + rt * 16 + lm) * NCH + ks * 32 + q * 8];

    float bbr[2][4];
#pragma unroll
    for (int rt = 0; rt < 2; ++rt)
#pragma unroll
        for (int r = 0; r < 4; ++r)
            bbr[rt][r] = bias[w * 32 + rt * 16 + q * 4 + r];

    const float* xb3 = x + (size_t)(b * NCH + w * 32) * NPIX + l;
    float fx[8][4];
    {   // prefetch tile 0
        const int n0 = blockIdx.x * 128;
#pragma unroll
        for (int rq = 0; rq < 8; ++rq) {
            const float* xb = xb3 + (size_t)(rq * 4) * NPIX + n0;
            fx[rq][0] = xb[0];
            fx[rq][1] = xb[NPIX];
            fx[rq][2] = xb[2 * NPIX];
            fx[rq][3] = xb[3 * NPIX];
        }
    }

    for (int jj = 0; jj < 2; ++jj) {
        // stage prefetched tile
#pragma unroll
        for (int rq = 0; rq < 8; ++rq) {
            bf16x4 pk;
            pk[0] = (__bf16)fx[rq][0]; pk[1] = (__bf16)fx[rq][1];
            pk[2] = (__bf16)fx[rq][2]; pk[3] = (__bf16)fx[rq][3];
            *(bf16x4*)&Xs[l][w * 32 + rq * 4] = pk;
        }
        if (jj == 0) {   // prefetch tile 1 (stays in flight across barrier)
            const int n1 = blockIdx.x * 128 + 64;
#pragma unroll
            for (int rq = 0; rq < 8; ++rq) {
                const float* xb = xb3 + (size_t)(rq * 4) * NPIX + n1;
                fx[rq][0] = xb[0];
                fx[rq][1] = xb[NPIX];
                fx[rq][2] = xb[2 * NPIX];
                fx[rq][3] = xb[3 * NPIX];
            }
        }
        barrier_lds();   // Xs ready

        f32x4 acc[2][4];
#pragma unroll
        for (int rt = 0; rt < 2; ++rt)
#pragma unroll
            for (int ct = 0; ct < 4; ++ct) acc[rt][ct] = (f32x4)0.f;

#pragma unroll
        for (int ks = 0; ks < 4; ++ks) {
            bf16x8 bf[4];
#pragma unroll
            for (int ct = 0; ct < 4; ++ct)
                bf[ct] = *(const bf16x8*)&Xs[ct * 16 + lm][ks * 32 + q * 8];
#pragma unroll
            for (int rt = 0; rt < 2; ++rt)
#pragma unroll
                for (int ct = 0; ct < 4; ++ct)
                    acc[rt][ct] = MFMA16(mfrag[rt][ks], bf[ct], acc[rt][ct]);
        }

        // ---- coalesced y epilogue: wave-private LDS transpose + dwordx4 ----
        const int n0  = blockIdx.x * 128 + jj * 64;
        const int rlo = l >> 4;            // 0..3
        const int px0 = (l & 15) * 4;      // 0,4,...,60
#pragma unroll
        for (int rt = 0; rt < 2; ++rt) {
#pragma unroll
            for (int ct = 0; ct < 4; ++ct)
#pragma unroll
                for (int r = 0; r < 4; ++r)
                    Ys[w][q * 4 + r][ct * 16 + lm] = acc[rt][ct][r] + bbr[rt][r];
            // same-wave LDS: compiler inserts lgkmcnt between write and read
#pragma unroll
            for (int i = 0; i < 4; ++i) {
                f32x4 v = *(const f32x4*)&Ys[w][i * 4 + rlo][px0];
                float* yp = y + (size_t)(b * NCH + w * 32 + rt * 16 + i * 4 + rlo) * NPIX
                          + n0 + px0;
                *(f32x4*)yp = v;
            }
        }
        barrier_lds();   // Xs consumed by all waves; safe to restage
    }
}

extern "C" void kernel_launch(void* const* d_in, const int* in_sizes, int n_in,
                              void* d_out, int out_size, void* d_ws, size_t ws_size,
                              hipStream_t stream) {
    (void)in_sizes; (void)n_in; (void)out_size; (void)ws_size;
    const float* x     = (const float*)d_in[0];
    const float* w_qkv = (const float*)d_in[1];
    const float* w_out = (const float*)d_in[2];
    const float* b_out = (const float*)d_in[3];
    float*  y   = (float*)d_out;
    float*  ws  = (float*)d_ws;
    __bf16* Mbf = (__bf16*)((char*)d_ws + WS_MBF_BYTE);

    // No memset needed: every Spart/Apart element is fully written by k1
    // before k2 reads it (slot-per-group, no atomics); k1->k2 and k2->k3
    // visibility is guaranteed by kernel dispatch boundaries.
    k1_partials<<<dim3(NSLOT, NBATCH),      256, 0, stream>>>(x, w_qkv, ws);
    k2_mprime  <<<dim3(NBATCH),             256, 0, stream>>>(w_qkv, w_out, ws, Mbf);
    k3_out     <<<dim3(NPIX / 128, NBATCH), 256, 0, stream>>>(x, b_out, Mbf, y);
}